// Round 3
// baseline (34222.238 us; speedup 1.0000x reference)
//
#include <hip/hip_runtime.h>

typedef unsigned short u16;
typedef unsigned int u32;
typedef unsigned long long u64;
typedef __attribute__((ext_vector_type(8))) short bf16x8;
typedef __attribute__((ext_vector_type(4))) float f32x4;

#define SCOPE_AGENT __HIP_MEMORY_SCOPE_AGENT

__device__ __forceinline__ float b2f(u16 x) {
  union { u32 u; float f; } c; c.u = ((u32)x) << 16; return c.f;
}
__device__ __forceinline__ u16 f2b(float f) {
  union { float f; u32 u; } c; c.f = f;
  u32 u = c.u;
  return (u16)((u + 0x7FFFu + ((u >> 16) & 1u)) >> 16);
}
__device__ __forceinline__ float sigf(float x) { return 1.f / (1.f + __expf(-x)); }
__device__ __forceinline__ float tanhfast(float x) {
  float e = __expf(2.f * x);
  return 1.f - 2.f / (e + 1.f);
}
__device__ __forceinline__ float clampf(float x, float b) {
  return fminf(fmaxf(x, -b), b);   // NaN -> -b (v_max returns non-NaN operand)
}
// dtype-agnostic input read: f32 buffer or bf16 buffer
__device__ __forceinline__ float loadin(const void* p, long i, u32 isf32) {
  return isf32 ? ((const float*)p)[i] : b2f(((const u16*)p)[i]);
}

// ---------------------------------------------------------------------------
// detect: decide whether float inputs are f32 or bf16 by scanning b_ih_l0
// (2048 elements). bf16 0.05-scale normals: no u16 has exponent>=0xC0.
// f32 raw bits read as u16 stream: ~25% of low-halves do. Also catch
// f32-containers-of-bf16-values via zero-low-half count.
// ---------------------------------------------------------------------------
__global__ __launch_bounds__(256) void detect_kernel(const u16* __restrict__ bih0,
                                                     u32* __restrict__ flag) {
  __shared__ u32 cnts[2];
  if (threadIdx.x < 2) cnts[threadIdx.x] = 0;
  __syncthreads();
  u32 huge = 0, zeros = 0;
  for (int i = threadIdx.x; i < 2048; i += 256) {
    u16 v = bih0[i];
    u32 e = (v >> 7) & 0xFFu;
    if (e >= 0xC0u) huge++;
    if (v == 0) zeros++;
  }
  atomicAdd(&cnts[0], huge);
  atomicAdd(&cnts[1], zeros);
  __syncthreads();
  if (threadIdx.x == 0) flag[0] = (cnts[0] >= 8u || cnts[1] >= 600u) ? 1u : 0u;
}

// ---------------------------------------------------------------------------
// prep: build gate-interleaved concatenated weights (bf16 canonical) + all
// canonical epilogue tensors. n' = j*4+g <-> orig row g*512+j.
// ---------------------------------------------------------------------------
__global__ __launch_bounds__(256) void prep_kernel(
    const void* __restrict__ Wih0, const void* __restrict__ Whh0,
    const void* __restrict__ bih0, const void* __restrict__ bhh0,
    const void* __restrict__ Wih1, const void* __restrict__ Whh1,
    const void* __restrict__ bih1, const void* __restrict__ bhh1,
    const void* __restrict__ W1, const void* __restrict__ b1,
    const void* __restrict__ W2, const void* __restrict__ b2,
    const void* __restrict__ Wf, const void* __restrict__ bfv,
    u16* __restrict__ Wcat0, u16* __restrict__ Wcat1,
    float* __restrict__ biasR0, float* __restrict__ biasR1,
    u16* __restrict__ W1c, float* __restrict__ b1c,
    float* __restrict__ W2c, float* __restrict__ b2c,
    float* __restrict__ Wfc, float* __restrict__ bfc,
    const u32* __restrict__ flag)
{
  const u32 isf32 = flag[0];
  const int gid = blockIdx.x * 256 + threadIdx.x;
  const int gsz = gridDim.x * 256;
  for (int i = gid; i < 2048 * 832; i += gsz) {
    int np = i / 832, k = i - np * 832;
    int g = np & 3, j = np >> 2;
    long orig = g * 512 + j;
    u16 v;
    if (k < 320) v = (k < 300) ? f2b(loadin(Wih0, orig * 300 + k, isf32)) : (u16)0;
    else         v = f2b(loadin(Whh0, orig * 512 + (k - 320), isf32));
    Wcat0[i] = v;
  }
  for (int i = gid; i < 2048 * 1024; i += gsz) {
    int np = i >> 10, k = i & 1023;
    int g = np & 3, j = np >> 2;
    long orig = g * 512 + j;
    Wcat1[i] = (k < 512) ? f2b(loadin(Wih1, orig * 512 + k, isf32))
                         : f2b(loadin(Whh1, orig * 512 + (k - 512), isf32));
  }
  for (int i = gid; i < 2048; i += gsz) {
    int g = i & 3, j = i >> 2;
    long orig = g * 512 + j;
    biasR0[i] = loadin(bih0, orig, isf32) + loadin(bhh0, orig, isf32);
    biasR1[i] = loadin(bih1, orig, isf32) + loadin(bhh1, orig, isf32);
  }
  for (int i = gid; i < 256 * 1024; i += gsz) W1c[i] = f2b(loadin(W1, i, isf32));
  for (int i = gid; i < 256; i += gsz) {
    b1c[i] = loadin(b1, i, isf32);
    W2c[i] = loadin(W2, i, isf32);
  }
  for (int i = gid; i < 1024; i += gsz) Wfc[i] = loadin(Wf, i, isf32);
  if (gid == 0) {
    b2c[0] = loadin(b2, 0, isf32);
    bfc[0] = loadin(bfv, 0, isf32);
  }
}

// ---------------------------------------------------------------------------
// gather: xpad[m = s*64+b][0..319] = embed[x_index[b][s]][0..299], zero pad
// ---------------------------------------------------------------------------
__global__ __launch_bounds__(256) void gather_kernel(
    const int* __restrict__ xi, const void* __restrict__ embed,
    u16* __restrict__ xpad, const u32* __restrict__ flag)
{
  const u32 isf32 = flag[0];
  const int r = blockIdx.x * 4 + (threadIdx.x >> 6);
  const int lane = threadIdx.x & 63;
  const int b = r & 63, s = r >> 6;
  const int idx = xi[b * 1024 + s];
  u16* drow = xpad + (u64)r * 320;
  if (!isf32) {
    const u32* src = (const u32*)((const u16*)embed + (u64)idx * 300);
    u32* dst = (u32*)drow;
    for (int c = lane; c < 150; c += 64) dst[c] = src[c];
  } else {
    const float* src = (const float*)embed + (u64)idx * 300;
    for (int c = lane; c < 300; c += 64) drow[c] = f2b(src[c]);
  }
  for (int c = 300 + lane; c < 320; c += 64) drow[c] = 0;
}

// ---------------------------------------------------------------------------
// Persistent LSTM layer. 64 WGs; WG w owns gate-cols [w*32,w*32+32) i.e.
// h-cols [w*8,w*8+8). Step barrier: monotone counter. Cross-XCD h traffic
// via agent-scope atomics; ordering via __syncthreads vmcnt drain.
// ---------------------------------------------------------------------------
__global__ __launch_bounds__(256, 1) void lstm_persist(
    const u16* __restrict__ X, int KX,
    const u16* __restrict__ Wcat,
    const float* __restrict__ biasR,
    u16* __restrict__ hs,
    u32* __restrict__ counter, int S)
{
  __shared__ __align__(16) u16 ldsW[32 * 1032];
  __shared__ __align__(16) u16 ldsH[64 * 520];
  __shared__ float ldsZ[64 * 33];
  __shared__ float ldsC[512];

  const int w = blockIdx.x;
  const int tid = threadIdx.x;
  const int lane = tid & 63;
  const int wv = tid >> 6;
  const int Kt = KX + 512;
  const int PW = Kt + 8;
  const int nu32 = Kt >> 1;

  {
    const u32* src = (const u32*)Wcat;
    u32* dst = (u32*)ldsW;
    const int pw2 = PW >> 1;
    for (int i = tid; i < 32 * nu32; i += 256) {
      int r = i / nu32, c = i - r * nu32;
      dst[r * pw2 + c] = src[(u64)(w * 32 + r) * nu32 + c];
    }
  }
  for (int i = tid; i < 512; i += 256) ldsC[i] = 0.f;
  __syncthreads();

  const int nksX = KX >> 5;
  const int xrow64 = KX >> 2;
  const int lrow = lane & 15;
  const int kq = lane >> 4;

  for (int t = 0; t < S; ++t) {
    f32x4 acc0 = {0.f, 0.f, 0.f, 0.f};
    f32x4 acc1 = {0.f, 0.f, 0.f, 0.f};

    {
      const u64* src = (const u64*)X + (u64)t * 64 * xrow64;
      u64* dst = (u64*)ldsH;
      for (int i = tid; i < 64 * xrow64; i += 256) {
        int r = i / xrow64, c = i - r * xrow64;
        dst[r * 130 + c] = src[i];
      }
    }
    __syncthreads();
    for (int ks = 0; ks < nksX; ++ks) {
      int k = ks * 32 + kq * 8;
      bf16x8 a  = *(const bf16x8*)&ldsH[(wv * 16 + lrow) * 520 + k];
      bf16x8 b0 = *(const bf16x8*)&ldsW[lrow * PW + k];
      bf16x8 b1 = *(const bf16x8*)&ldsW[(16 + lrow) * PW + k];
      acc0 = __builtin_amdgcn_mfma_f32_16x16x32_bf16(a, b0, acc0, 0, 0, 0);
      acc1 = __builtin_amdgcn_mfma_f32_16x16x32_bf16(a, b1, acc1, 0, 0, 0);
    }

    if (t > 0) {
      __syncthreads();
      if (tid == 0) {
        u32 target = 64u * (u32)t;
        while (__hip_atomic_load(counter, __ATOMIC_RELAXED, SCOPE_AGENT) < target)
          __builtin_amdgcn_s_sleep(2);
      }
      __syncthreads();
      {
        const u64* src = (const u64*)hs + (u64)(t - 1) * 8192;
        u64* dst = (u64*)ldsH;
        for (int i = tid; i < 8192; i += 256) {
          int r = i >> 7, c = i & 127;
          u64 v = __hip_atomic_load(src + i, __ATOMIC_RELAXED, SCOPE_AGENT);
          dst[r * 130 + c] = v;
        }
      }
      __syncthreads();
      for (int ks = 0; ks < 16; ++ks) {
        int k = ks * 32 + kq * 8;
        bf16x8 a  = *(const bf16x8*)&ldsH[(wv * 16 + lrow) * 520 + k];
        bf16x8 b0 = *(const bf16x8*)&ldsW[lrow * PW + KX + k];
        bf16x8 b1 = *(const bf16x8*)&ldsW[(16 + lrow) * PW + KX + k];
        acc0 = __builtin_amdgcn_mfma_f32_16x16x32_bf16(a, b0, acc0, 0, 0, 0);
        acc1 = __builtin_amdgcn_mfma_f32_16x16x32_bf16(a, b1, acc1, 0, 0, 0);
      }
    }

    {
      int col = lane & 15, q = lane >> 4;
#pragma unroll
      for (int r = 0; r < 4; ++r) {
        int m = wv * 16 + q * 4 + r;
        ldsZ[m * 33 + col] = acc0[r];
        ldsZ[m * 33 + 16 + col] = acc1[r];
      }
    }
    __syncthreads();

    {
      int b = tid >> 2;
      int j0 = (tid & 3) * 2;
      float hv[2];
#pragma unroll
      for (int q2 = 0; q2 < 2; ++q2) {
        int jl = j0 + q2;
        int cb = jl * 4;
        float zi = clampf(ldsZ[b * 33 + cb + 0] + biasR[w * 32 + cb + 0], 30.f);
        float zf = clampf(ldsZ[b * 33 + cb + 1] + biasR[w * 32 + cb + 1], 30.f);
        float zg = clampf(ldsZ[b * 33 + cb + 2] + biasR[w * 32 + cb + 2], 30.f);
        float zo = clampf(ldsZ[b * 33 + cb + 3] + biasR[w * 32 + cb + 3], 30.f);
        float co = ldsC[b * 8 + jl];
        float cn = clampf(sigf(zf) * co + sigf(zi) * tanhfast(zg), 64.f);
        ldsC[b * 8 + jl] = cn;
        hv[q2] = clampf(sigf(zo) * tanhfast(cn), 1.f);
      }
      u32 packed = (u32)f2b(hv[0]) | ((u32)f2b(hv[1]) << 16);
      u32* hdst = (u32*)(hs + (u64)(t * 64 + b) * 512 + w * 8 + j0);
      __hip_atomic_store(hdst, packed, __ATOMIC_RELAXED, SCOPE_AGENT);
    }
    __syncthreads();
    if (tid == 0)
      __hip_atomic_fetch_add(counter, 1u, __ATOMIC_RELAXED, SCOPE_AGENT);
  }
}

// ---------------------------------------------------------------------------
// gemm_bt: C[M,N](bf16) = A[M,K] @ B[N,K]^T. 128x128 tile. Full-K staging.
// ---------------------------------------------------------------------------
__global__ __launch_bounds__(256, 1) void gemm_bt(
    const u16* __restrict__ A, int lda,
    const u16* __restrict__ B, int ldb,
    u16* __restrict__ C, int ldc, int K)
{
  __shared__ __align__(16) u16 As[128 * 40];
  __shared__ __align__(16) u16 Bs[128 * 40];
  const int tid = threadIdx.x;
  const int bn = blockIdx.x * 128;
  const int bm = blockIdx.y * 128;
  const int lane = tid & 63;
  const int wv = tid >> 6;
  const int mh = wv >> 1, nh = wv & 1;
  const int lrow = lane & 15, kq = lane >> 4;
  const int sr = tid >> 1, sh = (tid & 1) * 16;
  f32x4 acc[4][4];
#pragma unroll
  for (int i = 0; i < 4; ++i)
#pragma unroll
    for (int j = 0; j < 4; ++j) acc[i][j] = {0.f, 0.f, 0.f, 0.f};

  for (int k0 = 0; k0 < K; k0 += 32) {
    *(bf16x8*)&As[sr * 40 + sh]     = *(const bf16x8*)(A + (u64)(bm + sr) * lda + k0 + sh);
    *(bf16x8*)&As[sr * 40 + sh + 8] = *(const bf16x8*)(A + (u64)(bm + sr) * lda + k0 + sh + 8);
    *(bf16x8*)&Bs[sr * 40 + sh]     = *(const bf16x8*)(B + (u64)(bn + sr) * ldb + k0 + sh);
    *(bf16x8*)&Bs[sr * 40 + sh + 8] = *(const bf16x8*)(B + (u64)(bn + sr) * ldb + k0 + sh + 8);
    __syncthreads();
    bf16x8 af[4], bfr[4];
#pragma unroll
    for (int mt = 0; mt < 4; ++mt)
      af[mt] = *(const bf16x8*)&As[(mh * 64 + mt * 16 + lrow) * 40 + kq * 8];
#pragma unroll
    for (int nt = 0; nt < 4; ++nt)
      bfr[nt] = *(const bf16x8*)&Bs[(nh * 64 + nt * 16 + lrow) * 40 + kq * 8];
#pragma unroll
    for (int mt = 0; mt < 4; ++mt)
#pragma unroll
      for (int nt = 0; nt < 4; ++nt)
        acc[mt][nt] = __builtin_amdgcn_mfma_f32_16x16x32_bf16(af[mt], bfr[nt], acc[mt][nt], 0, 0, 0);
    __syncthreads();
  }
#pragma unroll
  for (int mt = 0; mt < 4; ++mt)
#pragma unroll
    for (int nt = 0; nt < 4; ++nt)
#pragma unroll
      for (int r = 0; r < 4; ++r) {
        int m = bm + mh * 64 + mt * 16 + kq * 4 + r;
        int n = bn + nh * 64 + nt * 16 + lrow;
        C[(u64)m * ldc + n] = f2b(clampf(acc[mt][nt][r], 60.f));
      }
}

// ---------------------------------------------------------------------------
// part1[b][l] = b1[l] + sum_k h_N[b][k] * W1[l][k]   (W1 left half, K=512)
// ---------------------------------------------------------------------------
__global__ __launch_bounds__(256) void part1_kernel(
    const u16* __restrict__ h1s, const u16* __restrict__ W1c,
    const float* __restrict__ b1c, float* __restrict__ part1)
{
  __shared__ float hN[512];
  const int b = blockIdx.x;
  const int l = threadIdx.x;
  for (int i = l; i < 512; i += 256) hN[i] = b2f(h1s[(u64)(1023 * 64 + b) * 512 + i]);
  __syncthreads();
  const u16* wrow = W1c + (u64)l * 1024;
  float acc = b1c[l];
  for (int k = 0; k < 512; ++k) acc += hN[k] * b2f(wrow[k]);
  part1[b * 256 + l] = clampf(acc, 60.f);
}

// ---------------------------------------------------------------------------
// e[b][s] = sum_l tanh(part1[b][l] + part2[m][l]) * W2[l] + b2,  m = s*64+b
// ---------------------------------------------------------------------------
__global__ __launch_bounds__(256) void escore_kernel(
    const float* __restrict__ part1, const u16* __restrict__ part2,
    const float* __restrict__ W2c, const float* __restrict__ b2c,
    float* __restrict__ e)
{
  const int m = blockIdx.x * 4 + (threadIdx.x >> 6);
  const int lane = threadIdx.x & 63;
  const int b = m & 63, s = m >> 6;
  float acc = 0.f;
  for (int l = lane; l < 256; l += 64)
    acc += tanhfast(part1[b * 256 + l] + b2f(part2[(u64)m * 256 + l])) * W2c[l];
#pragma unroll
  for (int off = 32; off; off >>= 1) acc += __shfl_down(acc, off, 64);
  if (lane == 0) e[b * 1024 + s] = clampf(acc + b2c[0], 60.f);
}

// ---------------------------------------------------------------------------
// finish: softmax over s, write attn, context, sigmoid. Dual-dtype output.
// ---------------------------------------------------------------------------
__global__ __launch_bounds__(256) void finish_kernel(
    const float* __restrict__ e, const u16* __restrict__ h1s,
    const float* __restrict__ Wfc, const float* __restrict__ bfc,
    void* __restrict__ dout, const u32* __restrict__ flag)
{
  __shared__ float sw[1024];
  __shared__ float red[4];
  __shared__ float hN[512];
  const u32 isf32 = flag[0];
  const int b = blockIdx.x;
  const int tid = threadIdx.x;
  const int lane = tid & 63, wv = tid >> 6;

  float mx = -1e30f;
  for (int s = tid; s < 1024; s += 256) {
    float v = e[b * 1024 + s];
    sw[s] = v;
    mx = fmaxf(mx, v);
  }
#pragma unroll
  for (int off = 1; off < 64; off <<= 1) mx = fmaxf(mx, __shfl_xor(mx, off, 64));
  if (lane == 0) red[wv] = mx;
  __syncthreads();
  mx = fmaxf(fmaxf(red[0], red[1]), fmaxf(red[2], red[3]));
  __syncthreads();

  float sum = 0.f;
  for (int s = tid; s < 1024; s += 256) {
    float p = __expf(sw[s] - mx);
    sw[s] = p;
    sum += p;
  }
#pragma unroll
  for (int off = 1; off < 64; off <<= 1) sum += __shfl_xor(sum, off, 64);
  if (lane == 0) red[wv] = sum;
  __syncthreads();
  sum = red[0] + red[1] + red[2] + red[3];
  float inv = 1.f / sum;
  for (int s = tid; s < 1024; s += 256) {
    float wn = sw[s] * inv;
    sw[s] = wn;
    if (isf32) ((float*)dout)[b * 1024 + s] = wn;
    else       ((u16*)dout)[b * 1024 + s] = f2b(wn);
  }
  for (int i = tid; i < 512; i += 256) hN[i] = b2f(h1s[(u64)(1023 * 64 + b) * 512 + i]);
  __syncthreads();

  const int c0 = tid, c1 = tid + 256;
  float a0 = 0.f, a1 = 0.f;
  for (int s = 0; s < 1024; ++s) {
    const u16* hr = h1s + (u64)(s * 64 + b) * 512;
    float wn = sw[s];
    a0 += wn * b2f(hr[c0]);
    a1 += wn * b2f(hr[c1]);
  }
  float part = a0 * Wfc[c0] + a1 * Wfc[c1] + hN[c0] * Wfc[512 + c0] + hN[c1] * Wfc[512 + c1];
#pragma unroll
  for (int off = 1; off < 64; off <<= 1) part += __shfl_xor(part, off, 64);
  __syncthreads();
  if (lane == 0) red[wv] = part;
  __syncthreads();
  if (tid == 0) {
    float tot = clampf(red[0] + red[1] + red[2] + red[3] + bfc[0], 30.f);
    float o = sigf(tot);
    if (isf32) ((float*)dout)[65536 + b] = o;
    else       ((u16*)dout)[65536 + b] = f2b(o);
  }
}

// ---------------------------------------------------------------------------
extern "C" void kernel_launch(void* const* d_in, const int* in_sizes, int n_in,
                              void* d_out, int out_size, void* d_ws, size_t ws_size,
                              hipStream_t stream) {
  const int* x_index = (const int*)d_in[0];
  const void* embed = d_in[1];
  const void* Wih0 = d_in[2];
  const void* Whh0 = d_in[3];
  const void* bih0 = d_in[4];
  const void* bhh0 = d_in[5];
  const void* Wih1 = d_in[6];
  const void* Whh1 = d_in[7];
  const void* bih1 = d_in[8];
  const void* bhh1 = d_in[9];
  const void* W1 = d_in[10];
  const void* b1 = d_in[11];
  const void* W2 = d_in[12];
  const void* b2 = d_in[13];
  const void* Wf = d_in[14];
  const void* bfv = d_in[15];

  char* ws = (char*)d_ws;
  size_t off = 0;
  auto alloc = [&](size_t bytes) -> char* {
    char* p = ws + off;
    off += (bytes + 255) & ~(size_t)255;
    return p;
  };
  u32* cnt       = (u32*)alloc(256);
  u32* flag      = (u32*)alloc(256);
  float* biasR0  = (float*)alloc(2048 * 4);
  float* biasR1  = (float*)alloc(2048 * 4);
  float* part1   = (float*)alloc(64 * 256 * 4);
  float* e       = (float*)alloc(64 * 1024 * 4);
  float* b1c     = (float*)alloc(256 * 4);
  float* W2c     = (float*)alloc(256 * 4);
  float* b2c     = (float*)alloc(16);
  float* Wfc     = (float*)alloc(1024 * 4);
  float* bfc     = (float*)alloc(16);
  u16* W1c       = (u16*)alloc((size_t)256 * 1024 * 2);
  u16* Wcat0     = (u16*)alloc((size_t)2048 * 832 * 2);
  u16* Wcat1     = (u16*)alloc((size_t)2048 * 1024 * 2);
  u16* xpad      = (u16*)alloc((size_t)65536 * 320 * 2);
  u16* h0s       = (u16*)alloc((size_t)65536 * 512 * 2);
  u16* h1s       = (u16*)alloc((size_t)65536 * 512 * 2);
  u16* part2     = (u16*)alloc((size_t)65536 * 256 * 2);
  (void)ws_size; (void)in_sizes; (void)n_in; (void)out_size;

  hipMemsetAsync(cnt, 0, 256, stream);
  hipLaunchKernelGGL(detect_kernel, dim3(1), dim3(256), 0, stream,
                     (const u16*)bih0, flag);
  hipLaunchKernelGGL(prep_kernel, dim3(512), dim3(256), 0, stream,
                     Wih0, Whh0, bih0, bhh0, Wih1, Whh1, bih1, bhh1,
                     W1, b1, W2, b2, Wf, bfv,
                     Wcat0, Wcat1, biasR0, biasR1,
                     W1c, b1c, W2c, b2c, Wfc, bfc, flag);
  hipLaunchKernelGGL(gather_kernel, dim3(16384), dim3(256), 0, stream,
                     x_index, embed, xpad, flag);
  hipLaunchKernelGGL(lstm_persist, dim3(64), dim3(256), 0, stream,
                     xpad, 320, Wcat0, biasR0, h0s, cnt, 1024);
  hipLaunchKernelGGL(lstm_persist, dim3(64), dim3(256), 0, stream,
                     h0s, 512, Wcat1, biasR1, h1s, cnt + 16, 1024);
  hipLaunchKernelGGL(part1_kernel, dim3(64), dim3(256), 0, stream,
                     h1s, W1c, b1c, part1);
  hipLaunchKernelGGL(gemm_bt, dim3(2, 512), dim3(256), 0, stream,
                     h1s, 512, W1c + 512, 1024, part2, 256, 512);
  hipLaunchKernelGGL(escore_kernel, dim3(16384), dim3(256), 0, stream,
                     part1, part2, W2c, b2c, e);
  hipLaunchKernelGGL(finish_kernel, dim3(64), dim3(256), 0, stream,
                     e, h1s, Wfc, bfc, d_out, flag);
}

// Round 4
// 16429.385 us; speedup vs baseline: 2.0830x; 2.0830x over previous
//
#include <hip/hip_runtime.h>

typedef unsigned short u16;
typedef unsigned int u32;
typedef unsigned long long u64;
typedef __attribute__((ext_vector_type(8))) short bf16x8;
typedef __attribute__((ext_vector_type(4))) float f32x4;

#define SCOPE_AGENT __HIP_MEMORY_SCOPE_AGENT

__device__ __forceinline__ float b2f(u16 x) {
  union { u32 u; float f; } c; c.u = ((u32)x) << 16; return c.f;
}
__device__ __forceinline__ u16 f2b(float f) {
  union { float f; u32 u; } c; c.f = f;
  u32 u = c.u;
  return (u16)((u + 0x7FFFu + ((u >> 16) & 1u)) >> 16);
}
__device__ __forceinline__ float sigf(float x) { return 1.f / (1.f + __expf(-x)); }
__device__ __forceinline__ float tanhfast(float x) {
  float e = __expf(2.f * x);
  return 1.f - 2.f / (e + 1.f);
}
__device__ __forceinline__ float clampf(float x, float b) {
  return fminf(fmaxf(x, -b), b);
}
__device__ __forceinline__ float loadin(const void* p, long i, u32 isf32) {
  return isf32 ? ((const float*)p)[i] : b2f(((const u16*)p)[i]);
}
// L2-bypassing fresh read (sc0 sc1 -> fetch from L3/coherence point)
__device__ __forceinline__ u32 l3_load(const u32* p) {
  u32 v;
  asm volatile("global_load_dword %0, %1, off sc0 sc1\n\ts_waitcnt vmcnt(0)"
               : "=v"(v) : "v"(p) : "memory");
  return v;
}

// ---------------------------------------------------------------------------
// detect: f32 vs bf16 input discrimination on b_ih_l0 raw bits
// ---------------------------------------------------------------------------
__global__ __launch_bounds__(256) void detect_kernel(const u16* __restrict__ bih0,
                                                     u32* __restrict__ flag) {
  __shared__ u32 cnts[2];
  if (threadIdx.x < 2) cnts[threadIdx.x] = 0;
  __syncthreads();
  u32 huge = 0, zeros = 0;
  for (int i = threadIdx.x; i < 2048; i += 256) {
    u16 v = bih0[i];
    u32 e = (v >> 7) & 0xFFu;
    if (e >= 0xC0u) huge++;
    if (v == 0) zeros++;
  }
  atomicAdd(&cnts[0], huge);
  atomicAdd(&cnts[1], zeros);
  __syncthreads();
  if (threadIdx.x == 0) flag[0] = (cnts[0] >= 8u || cnts[1] >= 600u) ? 1u : 0u;
}

// ---------------------------------------------------------------------------
// prep: gate-interleaved concatenated weights + canonical epilogue tensors
// ---------------------------------------------------------------------------
__global__ __launch_bounds__(256) void prep_kernel(
    const void* __restrict__ Wih0, const void* __restrict__ Whh0,
    const void* __restrict__ bih0, const void* __restrict__ bhh0,
    const void* __restrict__ Wih1, const void* __restrict__ Whh1,
    const void* __restrict__ bih1, const void* __restrict__ bhh1,
    const void* __restrict__ W1, const void* __restrict__ b1,
    const void* __restrict__ W2, const void* __restrict__ b2,
    const void* __restrict__ Wf, const void* __restrict__ bfv,
    u16* __restrict__ Wcat0, u16* __restrict__ Wcat1,
    float* __restrict__ biasR0, float* __restrict__ biasR1,
    u16* __restrict__ W1c, float* __restrict__ b1c,
    float* __restrict__ W2c, float* __restrict__ b2c,
    float* __restrict__ Wfc, float* __restrict__ bfc,
    const u32* __restrict__ flag)
{
  const u32 isf32 = flag[0];
  const int gid = blockIdx.x * 256 + threadIdx.x;
  const int gsz = gridDim.x * 256;
  for (int i = gid; i < 2048 * 832; i += gsz) {
    int np = i / 832, k = i - np * 832;
    int g = np & 3, j = np >> 2;
    long orig = g * 512 + j;
    u16 v;
    if (k < 320) v = (k < 300) ? f2b(loadin(Wih0, orig * 300 + k, isf32)) : (u16)0;
    else         v = f2b(loadin(Whh0, orig * 512 + (k - 320), isf32));
    Wcat0[i] = v;
  }
  for (int i = gid; i < 2048 * 1024; i += gsz) {
    int np = i >> 10, k = i & 1023;
    int g = np & 3, j = np >> 2;
    long orig = g * 512 + j;
    Wcat1[i] = (k < 512) ? f2b(loadin(Wih1, orig * 512 + k, isf32))
                         : f2b(loadin(Whh1, orig * 512 + (k - 512), isf32));
  }
  for (int i = gid; i < 2048; i += gsz) {
    int g = i & 3, j = i >> 2;
    long orig = g * 512 + j;
    biasR0[i] = loadin(bih0, orig, isf32) + loadin(bhh0, orig, isf32);
    biasR1[i] = loadin(bih1, orig, isf32) + loadin(bhh1, orig, isf32);
  }
  for (int i = gid; i < 256 * 1024; i += gsz) W1c[i] = f2b(loadin(W1, i, isf32));
  for (int i = gid; i < 256; i += gsz) {
    b1c[i] = loadin(b1, i, isf32);
    W2c[i] = loadin(W2, i, isf32);
  }
  for (int i = gid; i < 1024; i += gsz) Wfc[i] = loadin(Wf, i, isf32);
  if (gid == 0) {
    b2c[0] = loadin(b2, 0, isf32);
    bfc[0] = loadin(bfv, 0, isf32);
  }
}

// ---------------------------------------------------------------------------
// gather: xpad[m = s*64+b][0..319] = embed[x_index[b][s]][0..299], zero pad
// ---------------------------------------------------------------------------
__global__ __launch_bounds__(256) void gather_kernel(
    const int* __restrict__ xi, const void* __restrict__ embed,
    u16* __restrict__ xpad, const u32* __restrict__ flag)
{
  const u32 isf32 = flag[0];
  const int r = blockIdx.x * 4 + (threadIdx.x >> 6);
  const int lane = threadIdx.x & 63;
  const int b = r & 63, s = r >> 6;
  const int idx = xi[b * 1024 + s];
  u16* drow = xpad + (u64)r * 320;
  if (!isf32) {
    const u32* src = (const u32*)((const u16*)embed + (u64)idx * 300);
    u32* dst = (u32*)drow;
    for (int c = lane; c < 150; c += 64) dst[c] = src[c];
  } else {
    const float* src = (const float*)embed + (u64)idx * 300;
    for (int c = lane; c < 300; c += 64) drow[c] = f2b(src[c]);
  }
  for (int c = 300 + lane; c < 320; c += 64) drow[c] = 0;
}

// ---------------------------------------------------------------------------
// Fused persistent 2-layer LSTM. 128 WGs: blocks 0-63 layer0, 64-127 layer1
// (lags 1 step, gated on layer0's counter). WG w owns gate-cols
// [w*32,w*32+32) == h-cols [w*8,w*8+8). Per-layer step barrier: monotone
// counter (RMW increments at L3; polls via sc0sc1 L2-bypass loads).
// h stores: agent-scope (write to L3). h/X stage loads: plain (compulsory
// first-touch per XCD -> fresh from L3; L2 dedups across WGs on an XCD).
// ---------------------------------------------------------------------------
__global__ __launch_bounds__(256, 1) void lstm_fused(
    const u16* __restrict__ xpad,
    const u16* __restrict__ Wcat0, const float* __restrict__ biasR0,
    const u16* __restrict__ Wcat1, const float* __restrict__ biasR1,
    u16* __restrict__ h0s, u16* __restrict__ h1s,
    u32* __restrict__ cnt0, u32* __restrict__ cnt1, int S)
{
  __shared__ __align__(16) u16 ldsW[32 * 1032];
  __shared__ __align__(16) u16 ldsH[64 * 520];
  __shared__ float ldsZ[64 * 33];
  __shared__ float ldsC[512];

  const int layer = blockIdx.x >> 6;
  const int w = blockIdx.x & 63;
  const u16* X = layer ? h0s : xpad;
  const int KX = layer ? 512 : 320;
  const u16* Wcat = layer ? Wcat1 : Wcat0;
  const float* biasR = layer ? biasR1 : biasR0;
  u16* hs = layer ? h1s : h0s;
  u32* cown = layer ? cnt1 : cnt0;

  const int tid = threadIdx.x;
  const int lane = tid & 63;
  const int wv = tid >> 6;
  const int Kt = KX + 512;
  const int PW = Kt + 8;
  const int nu32 = Kt >> 1;

  {   // weight slice rows w*32..w*32+31 -> LDS
    const u32* src = (const u32*)Wcat;
    u32* dst = (u32*)ldsW;
    const int pw2 = PW >> 1;
    for (int i = tid; i < 32 * nu32; i += 256) {
      int r = i / nu32, c = i - r * nu32;
      dst[r * pw2 + c] = src[(u64)(w * 32 + r) * nu32 + c];
    }
  }
  for (int i = tid; i < 512; i += 256) ldsC[i] = 0.f;
  __syncthreads();

  const int nksX = KX >> 5;
  const int xrow64 = KX >> 2;
  const int lrow = lane & 15;
  const int kq = lane >> 4;

  for (int t = 0; t < S; ++t) {
    f32x4 acc0 = {0.f, 0.f, 0.f, 0.f};
    f32x4 acc1 = {0.f, 0.f, 0.f, 0.f};

    // ---- layer-1 input gate: h0s rows for step t must be complete
    if (layer) {
      if (tid == 0) {
        u32 target = 64u * (u32)(t + 1);
        while (l3_load(cnt0) < target) __builtin_amdgcn_s_sleep(4);
      }
      __syncthreads();
    }

    // ---- phase 0: x-part
    {
      const u64* src = (const u64*)X + (u64)t * 64 * xrow64;
      u64* dst = (u64*)ldsH;
      for (int i = tid; i < 64 * xrow64; i += 256) {
        int r = i / xrow64, c = i - r * xrow64;
        dst[r * 130 + c] = src[i];
      }
    }
    __syncthreads();
    for (int ks = 0; ks < nksX; ++ks) {
      int k = ks * 32 + kq * 8;
      bf16x8 a  = *(const bf16x8*)&ldsH[(wv * 16 + lrow) * 520 + k];
      bf16x8 b0 = *(const bf16x8*)&ldsW[lrow * PW + k];
      bf16x8 b1 = *(const bf16x8*)&ldsW[(16 + lrow) * PW + k];
      acc0 = __builtin_amdgcn_mfma_f32_16x16x32_bf16(a, b0, acc0, 0, 0, 0);
      acc1 = __builtin_amdgcn_mfma_f32_16x16x32_bf16(a, b1, acc1, 0, 0, 0);
    }

    // ---- phase 1: recurrent part
    if (t > 0) {
      __syncthreads();            // all waves done reading x from ldsH
      if (tid == 0) {
        u32 target = 64u * (u32)t;
        while (l3_load(cown) < target) __builtin_amdgcn_s_sleep(4);
      }
      __syncthreads();
      {
        const u64* src = (const u64*)hs + (u64)(t - 1) * 8192;
        u64* dst = (u64*)ldsH;
        for (int i = tid; i < 8192; i += 256) {
          int r = i >> 7, c = i & 127;
          dst[r * 130 + c] = src[i];   // plain load: compulsory miss -> L3-fresh
        }
      }
      __syncthreads();
      for (int ks = 0; ks < 16; ++ks) {
        int k = ks * 32 + kq * 8;
        bf16x8 a  = *(const bf16x8*)&ldsH[(wv * 16 + lrow) * 520 + k];
        bf16x8 b0 = *(const bf16x8*)&ldsW[lrow * PW + KX + k];
        bf16x8 b1 = *(const bf16x8*)&ldsW[(16 + lrow) * PW + KX + k];
        acc0 = __builtin_amdgcn_mfma_f32_16x16x32_bf16(a, b0, acc0, 0, 0, 0);
        acc1 = __builtin_amdgcn_mfma_f32_16x16x32_bf16(a, b1, acc1, 0, 0, 0);
      }
    }

    // ---- z tiles -> LDS (C layout: col=lane&15, row=quad*4+reg)
    {
      int col = lane & 15, q = lane >> 4;
#pragma unroll
      for (int r = 0; r < 4; ++r) {
        int m = wv * 16 + q * 4 + r;
        ldsZ[m * 33 + col] = acc0[r];
        ldsZ[m * 33 + 16 + col] = acc1[r];
      }
    }
    __syncthreads();

    // ---- gates
    {
      int b = tid >> 2;
      int j0 = (tid & 3) * 2;
      float hv[2];
#pragma unroll
      for (int q2 = 0; q2 < 2; ++q2) {
        int jl = j0 + q2;
        int cb = jl * 4;
        float zi = clampf(ldsZ[b * 33 + cb + 0] + biasR[w * 32 + cb + 0], 30.f);
        float zf = clampf(ldsZ[b * 33 + cb + 1] + biasR[w * 32 + cb + 1], 30.f);
        float zg = clampf(ldsZ[b * 33 + cb + 2] + biasR[w * 32 + cb + 2], 30.f);
        float zo = clampf(ldsZ[b * 33 + cb + 3] + biasR[w * 32 + cb + 3], 30.f);
        float co = ldsC[b * 8 + jl];
        float cn = clampf(sigf(zf) * co + sigf(zi) * tanhfast(zg), 64.f);
        ldsC[b * 8 + jl] = cn;
        hv[q2] = clampf(sigf(zo) * tanhfast(cn), 1.f);
      }
      u32 packed = (u32)f2b(hv[0]) | ((u32)f2b(hv[1]) << 16);
      u32* hdst = (u32*)(hs + (u64)(t * 64 + b) * 512 + w * 8 + j0);
      __hip_atomic_store(hdst, packed, __ATOMIC_RELAXED, SCOPE_AGENT);
    }
    __syncthreads();   // vmcnt drain: h stores reach L3 before increment
    if (tid == 0)
      __hip_atomic_fetch_add(cown, 1u, __ATOMIC_RELAXED, SCOPE_AGENT);
  }
}

// ---------------------------------------------------------------------------
// gemm_bt: C[M,N](bf16) = A[M,K] @ B[N,K]^T. 128x128 tile.
// ---------------------------------------------------------------------------
__global__ __launch_bounds__(256, 1) void gemm_bt(
    const u16* __restrict__ A, int lda,
    const u16* __restrict__ B, int ldb,
    u16* __restrict__ C, int ldc, int K)
{
  __shared__ __align__(16) u16 As[128 * 40];
  __shared__ __align__(16) u16 Bs[128 * 40];
  const int tid = threadIdx.x;
  const int bn = blockIdx.x * 128;
  const int bm = blockIdx.y * 128;
  const int lane = tid & 63;
  const int wv = tid >> 6;
  const int mh = wv >> 1, nh = wv & 1;
  const int lrow = lane & 15, kq = lane >> 4;
  const int sr = tid >> 1, sh = (tid & 1) * 16;
  f32x4 acc[4][4];
#pragma unroll
  for (int i = 0; i < 4; ++i)
#pragma unroll
    for (int j = 0; j < 4; ++j) acc[i][j] = {0.f, 0.f, 0.f, 0.f};

  for (int k0 = 0; k0 < K; k0 += 32) {
    *(bf16x8*)&As[sr * 40 + sh]     = *(const bf16x8*)(A + (u64)(bm + sr) * lda + k0 + sh);
    *(bf16x8*)&As[sr * 40 + sh + 8] = *(const bf16x8*)(A + (u64)(bm + sr) * lda + k0 + sh + 8);
    *(bf16x8*)&Bs[sr * 40 + sh]     = *(const bf16x8*)(B + (u64)(bn + sr) * ldb + k0 + sh);
    *(bf16x8*)&Bs[sr * 40 + sh + 8] = *(const bf16x8*)(B + (u64)(bn + sr) * ldb + k0 + sh + 8);
    __syncthreads();
    bf16x8 af[4], bfr[4];
#pragma unroll
    for (int mt = 0; mt < 4; ++mt)
      af[mt] = *(const bf16x8*)&As[(mh * 64 + mt * 16 + lrow) * 40 + kq * 8];
#pragma unroll
    for (int nt = 0; nt < 4; ++nt)
      bfr[nt] = *(const bf16x8*)&Bs[(nh * 64 + nt * 16 + lrow) * 40 + kq * 8];
#pragma unroll
    for (int mt = 0; mt < 4; ++mt)
#pragma unroll
      for (int nt = 0; nt < 4; ++nt)
        acc[mt][nt] = __builtin_amdgcn_mfma_f32_16x16x32_bf16(af[mt], bfr[nt], acc[mt][nt], 0, 0, 0);
    __syncthreads();
  }
#pragma unroll
  for (int mt = 0; mt < 4; ++mt)
#pragma unroll
    for (int nt = 0; nt < 4; ++nt)
#pragma unroll
      for (int r = 0; r < 4; ++r) {
        int m = bm + mh * 64 + mt * 16 + kq * 4 + r;
        int n = bn + nh * 64 + nt * 16 + lrow;
        C[(u64)m * ldc + n] = f2b(clampf(acc[mt][nt][r], 60.f));
      }
}

// ---------------------------------------------------------------------------
// part1[b][l] = b1[l] + sum_k h_N[b][k] * W1[l][k]
// ---------------------------------------------------------------------------
__global__ __launch_bounds__(256) void part1_kernel(
    const u16* __restrict__ h1s, const u16* __restrict__ W1c,
    const float* __restrict__ b1c, float* __restrict__ part1)
{
  __shared__ float hN[512];
  const int b = blockIdx.x;
  const int l = threadIdx.x;
  for (int i = l; i < 512; i += 256) hN[i] = b2f(h1s[(u64)(1023 * 64 + b) * 512 + i]);
  __syncthreads();
  const u16* wrow = W1c + (u64)l * 1024;
  float acc = b1c[l];
  for (int k = 0; k < 512; ++k) acc += hN[k] * b2f(wrow[k]);
  part1[b * 256 + l] = clampf(acc, 60.f);
}

// ---------------------------------------------------------------------------
// e[b][s] = sum_l tanh(part1[b][l] + part2[m][l]) * W2[l] + b2,  m = s*64+b
// ---------------------------------------------------------------------------
__global__ __launch_bounds__(256) void escore_kernel(
    const float* __restrict__ part1, const u16* __restrict__ part2,
    const float* __restrict__ W2c, const float* __restrict__ b2c,
    float* __restrict__ e)
{
  const int m = blockIdx.x * 4 + (threadIdx.x >> 6);
  const int lane = threadIdx.x & 63;
  const int b = m & 63, s = m >> 6;
  float acc = 0.f;
  for (int l = lane; l < 256; l += 64)
    acc += tanhfast(part1[b * 256 + l] + b2f(part2[(u64)m * 256 + l])) * W2c[l];
#pragma unroll
  for (int off = 32; off; off >>= 1) acc += __shfl_down(acc, off, 64);
  if (lane == 0) e[b * 1024 + s] = clampf(acc + b2c[0], 60.f);
}

// ---------------------------------------------------------------------------
// finish: softmax, attn write, context, sigmoid. Dual-dtype output.
// ---------------------------------------------------------------------------
__global__ __launch_bounds__(256) void finish_kernel(
    const float* __restrict__ e, const u16* __restrict__ h1s,
    const float* __restrict__ Wfc, const float* __restrict__ bfc,
    void* __restrict__ dout, const u32* __restrict__ flag)
{
  __shared__ float sw[1024];
  __shared__ float red[4];
  __shared__ float hN[512];
  const u32 isf32 = flag[0];
  const int b = blockIdx.x;
  const int tid = threadIdx.x;
  const int lane = tid & 63, wv = tid >> 6;

  float mx = -1e30f;
  for (int s = tid; s < 1024; s += 256) {
    float v = e[b * 1024 + s];
    sw[s] = v;
    mx = fmaxf(mx, v);
  }
#pragma unroll
  for (int off = 1; off < 64; off <<= 1) mx = fmaxf(mx, __shfl_xor(mx, off, 64));
  if (lane == 0) red[wv] = mx;
  __syncthreads();
  mx = fmaxf(fmaxf(red[0], red[1]), fmaxf(red[2], red[3]));
  __syncthreads();

  float sum = 0.f;
  for (int s = tid; s < 1024; s += 256) {
    float p = __expf(sw[s] - mx);
    sw[s] = p;
    sum += p;
  }
#pragma unroll
  for (int off = 1; off < 64; off <<= 1) sum += __shfl_xor(sum, off, 64);
  if (lane == 0) red[wv] = sum;
  __syncthreads();
  sum = red[0] + red[1] + red[2] + red[3];
  float inv = 1.f / sum;
  for (int s = tid; s < 1024; s += 256) {
    float wn = sw[s] * inv;
    sw[s] = wn;
    if (isf32) ((float*)dout)[b * 1024 + s] = wn;
    else       ((u16*)dout)[b * 1024 + s] = f2b(wn);
  }
  for (int i = tid; i < 512; i += 256) hN[i] = b2f(h1s[(u64)(1023 * 64 + b) * 512 + i]);
  __syncthreads();

  const int c0 = tid, c1 = tid + 256;
  float a0 = 0.f, a1 = 0.f;
  for (int s = 0; s < 1024; ++s) {
    const u16* hr = h1s + (u64)(s * 64 + b) * 512;
    float wn = sw[s];
    a0 += wn * b2f(hr[c0]);
    a1 += wn * b2f(hr[c1]);
  }
  float part = a0 * Wfc[c0] + a1 * Wfc[c1] + hN[c0] * Wfc[512 + c0] + hN[c1] * Wfc[512 + c1];
#pragma unroll
  for (int off = 1; off < 64; off <<= 1) part += __shfl_xor(part, off, 64);
  __syncthreads();
  if (lane == 0) red[wv] = part;
  __syncthreads();
  if (tid == 0) {
    float tot = clampf(red[0] + red[1] + red[2] + red[3] + bfc[0], 30.f);
    float o = sigf(tot);
    if (isf32) ((float*)dout)[65536 + b] = o;
    else       ((u16*)dout)[65536 + b] = f2b(o);
  }
}

// ---------------------------------------------------------------------------
extern "C" void kernel_launch(void* const* d_in, const int* in_sizes, int n_in,
                              void* d_out, int out_size, void* d_ws, size_t ws_size,
                              hipStream_t stream) {
  const int* x_index = (const int*)d_in[0];
  const void* embed = d_in[1];
  const void* Wih0 = d_in[2];
  const void* Whh0 = d_in[3];
  const void* bih0 = d_in[4];
  const void* bhh0 = d_in[5];
  const void* Wih1 = d_in[6];
  const void* Whh1 = d_in[7];
  const void* bih1 = d_in[8];
  const void* bhh1 = d_in[9];
  const void* W1 = d_in[10];
  const void* b1 = d_in[11];
  const void* W2 = d_in[12];
  const void* b2 = d_in[13];
  const void* Wf = d_in[14];
  const void* bfv = d_in[15];

  char* ws = (char*)d_ws;
  size_t off = 0;
  auto alloc = [&](size_t bytes) -> char* {
    char* p = ws + off;
    off += (bytes + 255) & ~(size_t)255;
    return p;
  };
  u32* cnt       = (u32*)alloc(512);   // cnt0 = cnt, cnt1 = cnt+64 (256B apart)
  u32* flag      = (u32*)alloc(256);
  float* biasR0  = (float*)alloc(2048 * 4);
  float* biasR1  = (float*)alloc(2048 * 4);
  float* part1   = (float*)alloc(64 * 256 * 4);
  float* e       = (float*)alloc(64 * 1024 * 4);
  float* b1c     = (float*)alloc(256 * 4);
  float* W2c     = (float*)alloc(256 * 4);
  float* b2c     = (float*)alloc(16);
  float* Wfc     = (float*)alloc(1024 * 4);
  float* bfc     = (float*)alloc(16);
  u16* W1c       = (u16*)alloc((size_t)256 * 1024 * 2);
  u16* Wcat0     = (u16*)alloc((size_t)2048 * 832 * 2);
  u16* Wcat1     = (u16*)alloc((size_t)2048 * 1024 * 2);
  u16* xpad      = (u16*)alloc((size_t)65536 * 320 * 2);
  u16* h0s       = (u16*)alloc((size_t)65536 * 512 * 2);
  u16* h1s       = (u16*)alloc((size_t)65536 * 512 * 2);
  u16* part2     = (u16*)alloc((size_t)65536 * 256 * 2);
  (void)ws_size; (void)in_sizes; (void)n_in; (void)out_size;

  hipMemsetAsync(cnt, 0, 512, stream);
  hipLaunchKernelGGL(detect_kernel, dim3(1), dim3(256), 0, stream,
                     (const u16*)bih0, flag);
  hipLaunchKernelGGL(prep_kernel, dim3(512), dim3(256), 0, stream,
                     Wih0, Whh0, bih0, bhh0, Wih1, Whh1, bih1, bhh1,
                     W1, b1, W2, b2, Wf, bfv,
                     Wcat0, Wcat1, biasR0, biasR1,
                     W1c, b1c, W2c, b2c, Wfc, bfc, flag);
  hipLaunchKernelGGL(gather_kernel, dim3(16384), dim3(256), 0, stream,
                     x_index, embed, xpad, flag);
  hipLaunchKernelGGL(lstm_fused, dim3(128), dim3(256), 0, stream,
                     xpad, Wcat0, biasR0, Wcat1, biasR1,
                     h0s, h1s, cnt, cnt + 64, 1024);
  hipLaunchKernelGGL(part1_kernel, dim3(64), dim3(256), 0, stream,
                     h1s, W1c, b1c, part1);
  hipLaunchKernelGGL(gemm_bt, dim3(2, 512), dim3(256), 0, stream,
                     h1s, 512, W1c + 512, 1024, part2, 256, 512);
  hipLaunchKernelGGL(escore_kernel, dim3(16384), dim3(256), 0, stream,
                     part1, part2, W2c, b2c, e);
  hipLaunchKernelGGL(finish_kernel, dim3(64), dim3(256), 0, stream,
                     e, h1s, Wfc, bfc, d_out, flag);
}